// Round 2
// baseline (313.596 us; speedup 1.0000x reference)
//
#include <hip/hip_runtime.h>

// out[b,f] = x0[b,f] * dot(x[b,:], w) + bias[f] + x[b,f]
// B = 16384 rows, F = 2048 cols, fp32.
//
// Wave-per-row: each 64-lane wave owns one row; lane l owns float4 slots
// l + 64*i, i in [0,8). No LDS, no __syncthreads — the dot reduction is a
// 6-step __shfl_xor butterfly (every lane ends with the full sum). Waves are
// fully independent, so load latency of one wave overlaps reductions of
// another with no barrier drain.

#define F_DIM 2048
#define PER_LANE 8   // (F_DIM/4) float4 slots / 64 lanes

__global__ __launch_bounds__(256) void cross_wave_kernel(
    const float* __restrict__ x0,
    const float* __restrict__ x,
    const float* __restrict__ w,
    const float* __restrict__ bias,
    float* __restrict__ out)
{
    const int t    = threadIdx.x;
    const int wave = t >> 6;
    const int lane = t & 63;
    const int b    = blockIdx.x * 4 + wave;
    const long long row = (long long)b * F_DIM;

    const float4* __restrict__ x4  = (const float4*)(x  + row);
    const float4* __restrict__ x04 = (const float4*)(x0 + row);
    const float4* __restrict__ w4  = (const float4*)w;
    const float4* __restrict__ bi4 = (const float4*)bias;
    float4* __restrict__ o4 = (float4*)(out + row);

    float4 xv[PER_LANE], x0v[PER_LANE], wv[PER_LANE];

    // Issue all global loads up front: 24 independent 16B loads per lane.
    #pragma unroll
    for (int i = 0; i < PER_LANE; ++i) xv[i] = x4[lane + 64 * i];
    #pragma unroll
    for (int i = 0; i < PER_LANE; ++i) wv[i] = w4[lane + 64 * i];
    #pragma unroll
    for (int i = 0; i < PER_LANE; ++i) x0v[i] = x04[lane + 64 * i];

    float partial = 0.f;
    #pragma unroll
    for (int i = 0; i < PER_LANE; ++i) {
        partial += xv[i].x * wv[i].x + xv[i].y * wv[i].y
                 + xv[i].z * wv[i].z + xv[i].w * wv[i].w;
    }

    // Butterfly reduce across the 64-lane wave; all lanes get the sum.
    #pragma unroll
    for (int off = 1; off < 64; off <<= 1)
        partial += __shfl_xor(partial, off, 64);

    #pragma unroll
    for (int i = 0; i < PER_LANE; ++i) {
        float4 bv = bi4[lane + 64 * i];
        float4 o;
        o.x = x0v[i].x * partial + bv.x + xv[i].x;
        o.y = x0v[i].y * partial + bv.y + xv[i].y;
        o.z = x0v[i].z * partial + bv.z + xv[i].z;
        o.w = x0v[i].w * partial + bv.w + xv[i].w;
        o4[lane + 64 * i] = o;
    }
}

extern "C" void kernel_launch(void* const* d_in, const int* in_sizes, int n_in,
                              void* d_out, int out_size, void* d_ws, size_t ws_size,
                              hipStream_t stream) {
    const float* x0   = (const float*)d_in[0];
    const float* x    = (const float*)d_in[1];
    const float* w    = (const float*)d_in[2];
    const float* bias = (const float*)d_in[3];
    float* out = (float*)d_out;

    const int B = in_sizes[0] / F_DIM;          // 16384
    cross_wave_kernel<<<B / 4, 256, 0, stream>>>(x0, x, w, bias, out);
}

// Round 3
// 312.440 us; speedup vs baseline: 1.0037x; 1.0037x over previous
//
#include <hip/hip_runtime.h>

// out[b,f] = x0[b,f] * dot(x[b,:], w) + bias[f] + x[b,f]
// B = 16384 rows, F = 2048 cols, fp32.
//
// Wave-per-row, all 32 float4 loads issued up front and held in registers.
// __launch_bounds__(256, 3) gives the allocator ~170 VGPRs so the loads are
// NOT serialized into small vmcnt batches (R2's VGPR=48 showed the compiler
// was batching -> ~2-3 KB in flight/wave -> 2.4 TB/s cap).
// Reduction is DPP (VALU pipe, ~40 cyc) instead of ds_bpermute shuffles
// (~700 cyc on the LDS pipe), so waves return to issuing memory fast.

#define F_DIM 2048
#define PER_LANE 8   // (F_DIM/4) float4 slots / 64 lanes

__device__ __forceinline__ float wave_reduce_sum64(float v) {
    // LLVM atomic-optimizer style wave64 f32 sum: row_shr 1/2/4/8 within each
    // row of 16, then row_bcast15 / row_bcast31 to combine rows. Identity
    // (old) = 0 with bound_ctrl=false so out-of-range lanes add 0.
    v += __int_as_float(__builtin_amdgcn_update_dpp(
        0, __float_as_int(v), 0x111, 0xF, 0xF, false));   // row_shr:1
    v += __int_as_float(__builtin_amdgcn_update_dpp(
        0, __float_as_int(v), 0x112, 0xF, 0xF, false));   // row_shr:2
    v += __int_as_float(__builtin_amdgcn_update_dpp(
        0, __float_as_int(v), 0x114, 0xF, 0xF, false));   // row_shr:4
    v += __int_as_float(__builtin_amdgcn_update_dpp(
        0, __float_as_int(v), 0x118, 0xF, 0xF, false));   // row_shr:8
    v += __int_as_float(__builtin_amdgcn_update_dpp(
        0, __float_as_int(v), 0x142, 0xA, 0xF, false));   // row_bcast:15
    v += __int_as_float(__builtin_amdgcn_update_dpp(
        0, __float_as_int(v), 0x143, 0xC, 0xF, false));   // row_bcast:31
    // lane 63 holds the full 64-lane sum; broadcast via readlane (SGPR).
    return __int_as_float(__builtin_amdgcn_readlane(__float_as_int(v), 63));
}

__global__ __launch_bounds__(256, 3) void cross_wave_kernel(
    const float* __restrict__ x0,
    const float* __restrict__ x,
    const float* __restrict__ w,
    const float* __restrict__ bias,
    float* __restrict__ out)
{
    const int t    = threadIdx.x;
    const int wave = t >> 6;
    const int lane = t & 63;
    const int b    = blockIdx.x * 4 + wave;
    const long long row = (long long)b * F_DIM;

    const float4* __restrict__ x4  = (const float4*)(x  + row);
    const float4* __restrict__ x04 = (const float4*)(x0 + row);
    const float4* __restrict__ w4  = (const float4*)w;
    const float4* __restrict__ bi4 = (const float4*)bias;
    float4* __restrict__ o4 = (float4*)(out + row);

    float4 xv[PER_LANE], wv[PER_LANE], x0v[PER_LANE], bv[PER_LANE];

    // Issue ALL loads up front (32 x 16B per lane). Dot-critical streams
    // first, then the epilogue streams (x0, bias) as in-flight prefetch.
    #pragma unroll
    for (int i = 0; i < PER_LANE; ++i) xv[i]  = x4[lane + 64 * i];
    #pragma unroll
    for (int i = 0; i < PER_LANE; ++i) wv[i]  = w4[lane + 64 * i];
    #pragma unroll
    for (int i = 0; i < PER_LANE; ++i) x0v[i] = x04[lane + 64 * i];
    #pragma unroll
    for (int i = 0; i < PER_LANE; ++i) bv[i]  = bi4[lane + 64 * i];

    float partial = 0.f;
    #pragma unroll
    for (int i = 0; i < PER_LANE; ++i) {
        partial += xv[i].x * wv[i].x + xv[i].y * wv[i].y
                 + xv[i].z * wv[i].z + xv[i].w * wv[i].w;
    }

    const float dot = wave_reduce_sum64(partial);

    #pragma unroll
    for (int i = 0; i < PER_LANE; ++i) {
        float4 o;
        o.x = x0v[i].x * dot + bv[i].x + xv[i].x;
        o.y = x0v[i].y * dot + bv[i].y + xv[i].y;
        o.z = x0v[i].z * dot + bv[i].z + xv[i].z;
        o.w = x0v[i].w * dot + bv[i].w + xv[i].w;
        o4[lane + 64 * i] = o;
    }
}

extern "C" void kernel_launch(void* const* d_in, const int* in_sizes, int n_in,
                              void* d_out, int out_size, void* d_ws, size_t ws_size,
                              hipStream_t stream) {
    const float* x0   = (const float*)d_in[0];
    const float* x    = (const float*)d_in[1];
    const float* w    = (const float*)d_in[2];
    const float* bias = (const float*)d_in[3];
    float* out = (float*)d_out;

    const int B = in_sizes[0] / F_DIM;          // 16384
    cross_wave_kernel<<<B / 4, 256, 0, stream>>>(x0, x, w, bias, out);
}